// Round 4
// baseline (7553.326 us; speedup 1.0000x reference)
//
#include <hip/hip_runtime.h>
#include <math.h>

// Problem constants
static constexpr int cB = 32;
static constexpr int cT = 1024;
static constexpr int cH = 128;
static constexpr int cD = 256;   // 2H
static constexpr int cN = 2048;  // H*POOL
static constexpr int cM = cB * cT; // 32768

typedef __attribute__((ext_vector_type(8))) short short8;
typedef __attribute__((ext_vector_type(4))) float f32x4;

__device__ __forceinline__ ushort f2bf(float x) {
    union { float f; unsigned u; } v; v.f = x;
    unsigned r = v.u + 0x7FFF + ((v.u >> 16) & 1);   // RNE to bf16
    return (ushort)(r >> 16);
}
__device__ __forceinline__ float bf2f(ushort h) {
    union { float f; unsigned u; } v; v.u = ((unsigned)h) << 16;
    return v.f;
}

// ---------------------------------------------------------------------------
// Split-bf16 MFMA GEMM + 16-wide maxpool.
//   out[m][n16] = max_{p<16}( sum_k A[m][k]*B[k][n16*16+p] + initv[b][n16*16+p] )
// A given as bf16 hi/lo [M][K] row-major; B as bf16 hi/lo TRANSPOSED [N][K].
// 3-term split: ah*bh + ah*bl + al*bh  (fp32 MFMA accumulate).
// Block: 256 thr = 4 waves; block tile 128 rows x 128 cols; wave = 32 rows.
// mfma_f32_16x16x32_bf16 frags: A lane: row=l&15, k=kc+(l>>4)*8+j (16B row read)
//                               B lane: col=l&15, k=kc+(l>>4)*8+j (16B Wt row read)
//                               D lane: col=l&15, row=(l>>4)*4+reg
// Pool cols = lanes l&15  ->  4x shfl_xor max.
// No LDS: B panels are L2-resident (<=2MB), A rows L3-resident.
// ---------------------------------------------------------------------------
template<int K, bool WRITE_HL>
__global__ __launch_bounds__(256, 1)
void mfma_gemm_pool(const ushort* __restrict__ Ah, const ushort* __restrict__ Al,
                    const ushort* __restrict__ Bth, const ushort* __restrict__ Btl,
                    const float* __restrict__ initv, int init_bstride,
                    float* __restrict__ out, ushort* __restrict__ outh,
                    ushort* __restrict__ outl)
{
    const int tid  = threadIdx.x;
    const int wave = tid >> 6;
    const int lane = tid & 63;
    const int l15  = lane & 15;
    const int lg   = lane >> 4;                 // 0..3
    const int m0   = blockIdx.y * 128 + wave * 32;
    const int n0   = blockIdx.x * 128;
    const int brow = (blockIdx.y * 128) >> 10;  // batch (T=1024, 128|1024)

    // init values per n-frag: col = n0 + nf*16 + l15
    float iv[8];
    #pragma unroll
    for (int nf = 0; nf < 8; ++nf)
        iv[nf] = initv[(size_t)brow * init_bstride + n0 + nf * 16 + l15];

    f32x4 acc[2][8];
    #pragma unroll
    for (int mf = 0; mf < 2; ++mf)
        #pragma unroll
        for (int nf = 0; nf < 8; ++nf)
            acc[mf][nf] = (f32x4){0.f, 0.f, 0.f, 0.f};

    #pragma unroll 2
    for (int kc = 0; kc < K; kc += 32) {
        short8 a_h[2], a_l[2], b_h[8], b_l[8];
        #pragma unroll
        for (int mf = 0; mf < 2; ++mf) {
            size_t off = (size_t)(m0 + mf * 16 + l15) * K + kc + lg * 8;
            a_h[mf] = *(const short8*)(Ah + off);
            a_l[mf] = *(const short8*)(Al + off);
        }
        #pragma unroll
        for (int nf = 0; nf < 8; ++nf) {
            size_t off = (size_t)(n0 + nf * 16 + l15) * K + kc + lg * 8;
            b_h[nf] = *(const short8*)(Bth + off);
            b_l[nf] = *(const short8*)(Btl + off);
        }
        #pragma unroll
        for (int mf = 0; mf < 2; ++mf)
            #pragma unroll
            for (int nf = 0; nf < 8; ++nf) {
                acc[mf][nf] = __builtin_amdgcn_mfma_f32_16x16x32_bf16(
                    a_h[mf], b_h[nf], acc[mf][nf], 0, 0, 0);
                acc[mf][nf] = __builtin_amdgcn_mfma_f32_16x16x32_bf16(
                    a_h[mf], b_l[nf], acc[mf][nf], 0, 0, 0);
                acc[mf][nf] = __builtin_amdgcn_mfma_f32_16x16x32_bf16(
                    a_l[mf], b_h[nf], acc[mf][nf], 0, 0, 0);
            }
    }

    // epilogue: add init, maxpool over the 16 lanes of each n-frag, store
    const int NP = 128;  // pooled output width (2048/16)
    #pragma unroll
    for (int mf = 0; mf < 2; ++mf)
        #pragma unroll
        for (int nf = 0; nf < 8; ++nf)
            #pragma unroll
            for (int r = 0; r < 4; ++r) {
                float v = acc[mf][nf][r] + iv[nf];
                v = fmaxf(v, __shfl_xor(v, 1));
                v = fmaxf(v, __shfl_xor(v, 2));
                v = fmaxf(v, __shfl_xor(v, 4));
                v = fmaxf(v, __shfl_xor(v, 8));
                if (l15 == nf) {
                    int row = m0 + mf * 16 + lg * 4 + r;
                    int col = (n0 >> 4) + nf;
                    size_t o = (size_t)row * NP + col;
                    out[o] = v;
                    if (WRITE_HL) {
                        ushort hb = f2bf(v);
                        outh[o] = hb;
                        outl[o] = f2bf(v - bf2f(hb));
                    }
                }
            }
}

// ---------------------------------------------------------------------------
// Weight transpose + bf16 split: W[K x N] row-major -> Wt hi/lo [N][K]
// ---------------------------------------------------------------------------
__global__ void wsplit_kernel(const float* __restrict__ W, int K, int N,
                              ushort* __restrict__ th, ushort* __restrict__ tl)
{
    int idx = blockIdx.x * 256 + threadIdx.x;
    if (idx >= K * N) return;
    int k = idx / N, n = idx - k * N;      // coalesced read
    float x = W[idx];
    ushort h = f2bf(x);
    th[(size_t)n * K + k] = h;
    tl[(size_t)n * K + k] = f2bf(x - bf2f(h));
}

// ---------------------------------------------------------------------------
// U split: U fp32 [M][256] -> Uh/Ul bf16 same layout
// ---------------------------------------------------------------------------
__global__ void usplit_kernel(const float* __restrict__ U,
                              ushort* __restrict__ uh, ushort* __restrict__ ul)
{
    int idx = blockIdx.x * 256 + threadIdx.x;   // cM*cD threads
    float x = U[idx];
    ushort h = f2bf(x);
    uh[idx] = h;
    ul[idx] = f2bf(x - bf2f(h));
}

// ---------------------------------------------------------------------------
// r[b][j] = tanh( concat([h,us,ue])[b] . WDw[:,j] + WDb[j] )
// ---------------------------------------------------------------------------
__global__ void r_kernel(const float* __restrict__ h, const float* __restrict__ us,
                         const float* __restrict__ ue,
                         const float* __restrict__ WDw, const float* __restrict__ WDb,
                         float* __restrict__ r)
{
    int b = blockIdx.x;
    int j = threadIdx.x;  // 128 threads
    __shared__ float x[640];
    x[j]       = h[b * cH + j];
    x[128 + j] = us[b * cD + j];
    x[256 + j] = us[b * cD + 128 + j];
    x[384 + j] = ue[b * cD + j];
    x[512 + j] = ue[b * cD + 128 + j];
    __syncthreads();
    float s = WDb[j];
    for (int k = 0; k < 640; ++k) s = fmaf(x[k], WDw[(size_t)k * cH + j], s);
    r[b * cH + j] = tanhf(s);
}

// ---------------------------------------------------------------------------
// rterm[b][n] = r[b] . W1r[:,n] + W1b[n]    (W1r = rows 256..383 of W1w)
// ---------------------------------------------------------------------------
__global__ void rterm_kernel(const float* __restrict__ r, const float* __restrict__ W1r,
                             const float* __restrict__ W1b, float* __restrict__ rterm)
{
    int b = blockIdx.y;
    int n = blockIdx.x * 256 + threadIdx.x;  // grid (8,32)
    __shared__ float rs[128];
    if (threadIdx.x < 128) rs[threadIdx.x] = r[b * cH + threadIdx.x];
    __syncthreads();
    float s = W1b[n];
    for (int k = 0; k < 128; ++k) s = fmaf(rs[k], W1r[(size_t)k * cN + n], s);
    rterm[(size_t)b * cN + n] = s;
}

// ---------------------------------------------------------------------------
// score[m] = max_p( concat([m1,m2])[m] . W3w[:,p] + W3b[p] ) -> ent region
// ---------------------------------------------------------------------------
__global__ __launch_bounds__(256)
void score_kernel(const float* __restrict__ m1, const float* __restrict__ m2,
                  const float* __restrict__ W3w, const float* __restrict__ W3b,
                  float* __restrict__ ent)
{
    __shared__ float xs[16][257];
    __shared__ float wsh[256 * 16];
    int tid = threadIdx.x;
    int m0 = blockIdx.x * 16;
    #pragma unroll
    for (int q = 0; q < 16; ++q) wsh[tid + q * 256] = W3w[tid + q * 256];
    #pragma unroll
    for (int q = 0; q < 8; ++q) {
        int f = tid + q * 256;
        int rl = f >> 7, col = f & 127;
        xs[rl][col]       = m1[(size_t)(m0 + rl) * cH + col];
        xs[rl][128 + col] = m2[(size_t)(m0 + rl) * cH + col];
    }
    __syncthreads();
    int rl = tid >> 4, p = tid & 15;
    float s = W3b[p];
    for (int k = 0; k < 256; ++k) s = fmaf(xs[rl][k], wsh[k * 16 + p], s);
    #pragma unroll
    for (int off = 8; off; off >>= 1) s = fmaxf(s, __shfl_xor(s, off));
    if (p == 0) ent[m0 + rl] = s;
}

// ---------------------------------------------------------------------------
// argmax over T per batch (first-occurrence ties), write float index,
// gather U row into us/ue
// ---------------------------------------------------------------------------
__global__ void argmax_kernel(const float* __restrict__ sc, const float* __restrict__ U,
                              float* __restrict__ uvec, float* __restrict__ outidx)
{
    int b = blockIdx.x;
    int tid = threadIdx.x;  // 256
    float bv = -3.4e38f;
    int bi = 0x7fffffff;
    for (int t = tid; t < cT; t += 256) {
        float v = sc[b * cT + t];
        if (v > bv || (v == bv && t < bi)) { bv = v; bi = t; }
    }
    __shared__ float vs[256];
    __shared__ int   is[256];
    vs[tid] = bv; is[tid] = bi;
    __syncthreads();
    for (int s = 128; s > 0; s >>= 1) {
        if (tid < s) {
            if (vs[tid + s] > vs[tid] ||
                (vs[tid + s] == vs[tid] && is[tid + s] < is[tid])) {
                vs[tid] = vs[tid + s];
                is[tid] = is[tid + s];
            }
        }
        __syncthreads();
    }
    int best = is[0];
    if (tid == 0) outidx[b] = (float)best;
    uvec[b * cD + tid % cD] = U[((size_t)b * cT + best) * cD + (tid % cD)];
}

// ---------------------------------------------------------------------------
// LSTM cell
// ---------------------------------------------------------------------------
__global__ void lstm_kernel(const float* __restrict__ us, const float* __restrict__ ue,
                            float* __restrict__ h, float* __restrict__ c,
                            const float* __restrict__ wih, const float* __restrict__ whh,
                            const float* __restrict__ bih, const float* __restrict__ bhh)
{
    int b = blockIdx.x;
    int j = threadIdx.x;  // 128
    __shared__ float x[512];
    __shared__ float hh[128];
    x[j]       = us[b * cD + j];
    x[128 + j] = us[b * cD + 128 + j];
    x[256 + j] = ue[b * cD + j];
    x[384 + j] = ue[b * cD + 128 + j];
    hh[j] = h[b * cH + j];
    __syncthreads();
    float g4[4];
    #pragma unroll
    for (int gi = 0; gi < 4; ++gi) {
        int row = gi * 128 + j;
        float s = bih[row] + bhh[row];
        const float* wr = wih + (size_t)row * 512;
        for (int k = 0; k < 512; ++k) s = fmaf(x[k], wr[k], s);
        const float* wr2 = whh + (size_t)row * 128;
        for (int k = 0; k < 128; ++k) s = fmaf(hh[k], wr2[k], s);
        g4[gi] = s;
    }
    float i_ = 1.f / (1.f + expf(-g4[0]));
    float f_ = 1.f / (1.f + expf(-g4[1]));
    float g_ = tanhf(g4[2]);
    float o_ = 1.f / (1.f + expf(-g4[3]));
    float c2 = f_ * c[b * cH + j] + i_ * g_;
    float h2 = o_ * tanhf(c2);
    c[b * cH + j] = c2;
    h[b * cH + j] = h2;
}

__global__ void init_kernel(const float* __restrict__ U, float* __restrict__ us,
                            float* __restrict__ ue, float* __restrict__ h,
                            float* __restrict__ c)
{
    int i = blockIdx.x * 256 + threadIdx.x;  // 8192 threads
    if (i < cB * cD) {
        int b = i >> 8, d = i & 255;
        us[i] = U[((size_t)b * cT + 0) * cD + d];
        ue[i] = U[((size_t)b * cT + 1) * cD + d];
    }
    if (i < cB * cH) { h[i] = 0.f; c[i] = 0.f; }
}

// ---------------------------------------------------------------------------
extern "C" void kernel_launch(void* const* d_in, const int* in_sizes, int n_in,
                              void* d_out, int out_size, void* d_ws, size_t ws_size,
                              hipStream_t stream)
{
    const float* U = (const float*)d_in[0];
    const float* WD_w[2] = {(const float*)d_in[1], (const float*)d_in[9]};
    const float* WD_b[2] = {(const float*)d_in[2], (const float*)d_in[10]};
    const float* W1_w[2] = {(const float*)d_in[3], (const float*)d_in[11]};
    const float* W1_b[2] = {(const float*)d_in[4], (const float*)d_in[12]};
    const float* W2_w[2] = {(const float*)d_in[5], (const float*)d_in[13]};
    const float* W2_b[2] = {(const float*)d_in[6], (const float*)d_in[14]};
    const float* W3_w[2] = {(const float*)d_in[7], (const float*)d_in[15]};
    const float* W3_b[2] = {(const float*)d_in[8], (const float*)d_in[16]};
    const float* wih = (const float*)d_in[17];
    const float* whh = (const float*)d_in[18];
    const float* bih = (const float*)d_in[19];
    const float* bhh = (const float*)d_in[20];

    float* ws = (float*)d_ws;
    float* m1 = ws;                               // 4M floats
    float* m2 = m1 + (size_t)cM * cH;             // 4M
    float* us = m2 + (size_t)cM * cH;
    float* ue = us + cB * cD;
    float* h  = ue + cB * cD;
    float* c  = h + cB * cH;
    float* r  = c + cB * cH;
    float* rterm = r + cB * cH;                   // 64K
    float* cur = rterm + (size_t)cB * cN;

    ushort* m1h = (ushort*)cur;                   cur += (size_t)cM * cH / 2;
    ushort* m1l = (ushort*)cur;                   cur += (size_t)cM * cH / 2;
    ushort* Uh  = (ushort*)cur;                   cur += (size_t)cM * cD / 2;
    ushort* Ul  = (ushort*)cur;                   cur += (size_t)cM * cD / 2;
    ushort* W1th[2], *W1tl[2], *W2th[2], *W2tl[2];
    for (int sd = 0; sd < 2; ++sd) {
        W1th[sd] = (ushort*)cur; cur += (size_t)cN * cD / 2;   // [2048][256]
        W1tl[sd] = (ushort*)cur; cur += (size_t)cN * cD / 2;
        W2th[sd] = (ushort*)cur; cur += (size_t)cN * cH / 2;   // [2048][128]
        W2tl[sd] = (ushort*)cur; cur += (size_t)cN * cH / 2;
    }

    float* outf = (float*)d_out;

    init_kernel<<<32, 256, 0, stream>>>(U, us, ue, h, c);
    usplit_kernel<<<(cM * cD) / 256, 256, 0, stream>>>(U, Uh, Ul);
    for (int sd = 0; sd < 2; ++sd) {
        wsplit_kernel<<<(cD * cN) / 256, 256, 0, stream>>>(
            W1_w[sd], cD, cN, W1th[sd], W1tl[sd]);     // first 256 rows of W1
        wsplit_kernel<<<(cH * cN) / 256, 256, 0, stream>>>(
            W2_w[sd], cH, cN, W2th[sd], W2tl[sd]);
    }

    dim3 ggrid(cN / 128, cM / 128);   // 16 x 256
    for (int it = 0; it < 4; ++it) {
        for (int sd = 0; sd < 2; ++sd) {
            r_kernel<<<32, 128, 0, stream>>>(h, us, ue, WD_w[sd], WD_b[sd], r);
            rterm_kernel<<<dim3(8, 32), 256, 0, stream>>>(
                r, W1_w[sd] + (size_t)256 * cN, W1_b[sd], rterm);
            // m1 = pool(U @ W1[0:256] + rterm)  -> fp32 + bf16 hi/lo
            mfma_gemm_pool<256, true><<<ggrid, 256, 0, stream>>>(
                Uh, Ul, W1th[sd], W1tl[sd], rterm, cN, m1, m1h, m1l);
            // m2 = pool(m1 @ W2 + b2) -> fp32
            mfma_gemm_pool<128, false><<<ggrid, 256, 0, stream>>>(
                m1h, m1l, W2th[sd], W2tl[sd], W2_b[sd], 0, m2, nullptr, nullptr);
            float* ent = outf + 64 + (size_t)(it * 2 + sd) * cB * cT;
            score_kernel<<<2048, 256, 0, stream>>>(m1, m2, W3_w[sd], W3_b[sd], ent);
            argmax_kernel<<<32, 256, 0, stream>>>(ent, U, sd ? ue : us,
                                                  outf + (sd ? 32 : 0));
        }
        lstm_kernel<<<32, 128, 0, stream>>>(us, ue, h, c, wih, whh, bih, bhh);
    }
}

// Round 5
// 2887.022 us; speedup vs baseline: 2.6163x; 2.6163x over previous
//
#include <hip/hip_runtime.h>
#include <math.h>

// Problem constants
static constexpr int cB = 32;
static constexpr int cT = 1024;
static constexpr int cH = 128;
static constexpr int cD = 256;   // 2H
static constexpr int cN = 2048;  // H*POOL
static constexpr int cM = cB * cT; // 32768

typedef __attribute__((ext_vector_type(8))) short short8;
typedef __attribute__((ext_vector_type(4))) float f32x4;

__device__ __forceinline__ ushort f2bf(float x) {
    union { float f; unsigned u; } v; v.f = x;
    unsigned r = v.u + 0x7FFF + ((v.u >> 16) & 1);   // RNE to bf16
    return (ushort)(r >> 16);
}
__device__ __forceinline__ float bf2f(ushort h) {
    union { float f; unsigned u; } v; v.u = ((unsigned)h) << 16;
    return v.f;
}

// async global->LDS, 16B per lane, wave-uniform LDS base + lane*16
__device__ __forceinline__ void gload_lds16(const ushort* g, ushort* l) {
    __builtin_amdgcn_global_load_lds(
        (const __attribute__((address_space(1))) unsigned int*)(const void*)g,
        (__attribute__((address_space(3))) unsigned int*)(void*)l,
        16, 0, 0);
}

// ---------------------------------------------------------------------------
// Split-bf16 MFMA GEMM, LDS-staged (m97 structure), optional 16-pool epilogue.
//   C = maybe_pool( A[M x K] @ B[K x N] + initv[brow x N or broadcast] )
// A: bf16 hi/lo [M][K] row-major. B: bf16 hi/lo TRANSPOSED [N][K].
// 3-term split: ah*bh + ah*bl + al*bh, fp32 MFMA accumulate.
// Block 256 thr = 4 waves (2x2), tile 128x128, BK=32; wave tile 64x64
// (4x4 frags of 16x16x32). LDS: 4 planes [128][32] ushort = 32KB, filled by
// global_load_lds(16B) with chunk-XOR swizzle applied on the GLOBAL source
// (linear LDS dest) and the same XOR on ds_read -> 4-way residual conflict.
// ---------------------------------------------------------------------------
template<int K, bool POOL, bool WRITE_HL>
__global__ __launch_bounds__(256, 2)
void mfma_gemm(const ushort* __restrict__ Ah, const ushort* __restrict__ Al,
               const ushort* __restrict__ Bth, const ushort* __restrict__ Btl,
               const float* __restrict__ initv, int init_bstride,
               float* __restrict__ out, ushort* __restrict__ outh,
               ushort* __restrict__ outl)
{
    __shared__ __attribute__((aligned(16))) ushort sAh[128 * 32];
    __shared__ __attribute__((aligned(16))) ushort sAl[128 * 32];
    __shared__ __attribute__((aligned(16))) ushort sBh[128 * 32];
    __shared__ __attribute__((aligned(16))) ushort sBl[128 * 32];

    const int tid  = threadIdx.x;
    const int wave = tid >> 6;
    const int lane = tid & 63;
    const int l15  = lane & 15;
    const int lg   = lane >> 4;         // 0..3 -> k-chunk
    const int wr   = wave >> 1;         // wave row (0..1)
    const int wc   = wave & 1;          // wave col (0..1)
    const int m0   = blockIdx.y * 128;
    const int n0   = blockIdx.x * 128;
    const int brow = m0 >> 10;          // batch row (T=1024)

    // init values per n-frag: col = n0 + wc*64 + nf*16 + l15
    float iv[4] = {0.f, 0.f, 0.f, 0.f};
    if (initv) {
        #pragma unroll
        for (int nf = 0; nf < 4; ++nf)
            iv[nf] = initv[(size_t)brow * init_bstride + n0 + wc * 64 + nf * 16 + l15];
    }

    f32x4 acc[4][4];
    #pragma unroll
    for (int mf = 0; mf < 4; ++mf)
        #pragma unroll
        for (int nf = 0; nf < 4; ++nf)
            acc[mf][nf] = (f32x4){0.f, 0.f, 0.f, 0.f};

    // staging decomposition: per plane, 8 wave-instructions of 1KB
    // instr i covers rows 16i..16i+15; lane -> row 16i+(l>>2), chunk pos l&3
    const int st_row_in = lane >> 2;        // 0..15
    const int st_pos    = lane & 3;         // stored chunk position

    for (int kc = 0; kc < K; kc += 32) {
        #pragma unroll
        for (int q = 0; q < 4; ++q) {
            const ushort* gsrc = (q == 0) ? Ah : (q == 1) ? Al : (q == 2) ? Bth : Btl;
            ushort* lbase = (q == 0) ? sAh : (q == 1) ? sAl : (q == 2) ? sBh : sBl;
            const int rb = (q < 2) ? m0 : n0;
            #pragma unroll
            for (int i2 = 0; i2 < 2; ++i2) {
                int i   = wave * 2 + i2;            // 0..7
                int row = i * 16 + st_row_in;
                int cl  = st_pos ^ (row & 3);       // logical k-chunk for this slot
                gload_lds16(gsrc + (size_t)(rb + row) * K + kc + cl * 8,
                            lbase + i * 512);
            }
        }
        __syncthreads();   // drains vmcnt -> LDS valid

        short8 a_h[4], a_l[4], b_h[4], b_l[4];
        #pragma unroll
        for (int mf = 0; mf < 4; ++mf) {
            int row  = wr * 64 + mf * 16 + l15;
            int addr = row * 32 + ((lg ^ (row & 3)) * 8);
            a_h[mf] = *(const short8*)(sAh + addr);
            a_l[mf] = *(const short8*)(sAl + addr);
        }
        #pragma unroll
        for (int nf = 0; nf < 4; ++nf) {
            int row  = wc * 64 + nf * 16 + l15;
            int addr = row * 32 + ((lg ^ (row & 3)) * 8);
            b_h[nf] = *(const short8*)(sBh + addr);
            b_l[nf] = *(const short8*)(sBl + addr);
        }

        #pragma unroll
        for (int mf = 0; mf < 4; ++mf)
            #pragma unroll
            for (int nf = 0; nf < 4; ++nf) {
                acc[mf][nf] = __builtin_amdgcn_mfma_f32_16x16x32_bf16(
                    a_h[mf], b_h[nf], acc[mf][nf], 0, 0, 0);
                acc[mf][nf] = __builtin_amdgcn_mfma_f32_16x16x32_bf16(
                    a_h[mf], b_l[nf], acc[mf][nf], 0, 0, 0);
                acc[mf][nf] = __builtin_amdgcn_mfma_f32_16x16x32_bf16(
                    a_l[mf], b_h[nf], acc[mf][nf], 0, 0, 0);
            }
        __syncthreads();   // protect LDS reuse
    }

    if (POOL) {
        const int NP = 128;
        #pragma unroll
        for (int mf = 0; mf < 4; ++mf)
            #pragma unroll
            for (int nf = 0; nf < 4; ++nf)
                #pragma unroll
                for (int r = 0; r < 4; ++r) {
                    float v = acc[mf][nf][r] + iv[nf];
                    v = fmaxf(v, __shfl_xor(v, 1));
                    v = fmaxf(v, __shfl_xor(v, 2));
                    v = fmaxf(v, __shfl_xor(v, 4));
                    v = fmaxf(v, __shfl_xor(v, 8));
                    if (l15 == nf) {
                        int row = m0 + wr * 64 + mf * 16 + lg * 4 + r;
                        int col = ((n0 + wc * 64) >> 4) + nf;
                        size_t o = (size_t)row * NP + col;
                        out[o] = v;
                        if (WRITE_HL) {
                            ushort hb = f2bf(v);
                            outh[o] = hb;
                            outl[o] = f2bf(v - bf2f(hb));
                        }
                    }
                }
    } else {
        #pragma unroll
        for (int mf = 0; mf < 4; ++mf)
            #pragma unroll
            for (int nf = 0; nf < 4; ++nf) {
                int col = n0 + wc * 64 + nf * 16 + l15;
                #pragma unroll
                for (int r = 0; r < 4; ++r) {
                    int row = m0 + wr * 64 + mf * 16 + lg * 4 + r;
                    out[(size_t)row * cN + col] = acc[mf][nf][r] + iv[nf];
                }
            }
    }
}

// ---------------------------------------------------------------------------
// m1[m][o] = max_p( A1[m][o*16+p] + rterm[b][o*16+p] ), also emits bf16 hi/lo
// ---------------------------------------------------------------------------
__global__ void m1_from_a1_kernel(const float* __restrict__ A1,
                                  const float* __restrict__ rterm,
                                  float* __restrict__ m1,
                                  ushort* __restrict__ m1h,
                                  ushort* __restrict__ m1l)
{
    int idx = blockIdx.x * 256 + threadIdx.x;   // [0, 32768*128)
    int m = idx >> 7;
    int o = idx & 127;
    int b = m >> 10;
    const float4* a  = (const float4*)(A1 + (size_t)m * cN + o * 16);
    const float4* rt = (const float4*)(rterm + (size_t)b * cN + o * 16);
    float mx = -3.4e38f;
    #pragma unroll
    for (int q = 0; q < 4; ++q) {
        float4 av = a[q];
        float4 rv = rt[q];
        mx = fmaxf(mx, fmaxf(fmaxf(av.x + rv.x, av.y + rv.y),
                             fmaxf(av.z + rv.z, av.w + rv.w)));
    }
    m1[idx] = mx;
    ushort hb = f2bf(mx);
    m1h[idx] = hb;
    m1l[idx] = f2bf(mx - bf2f(hb));
}

// ---------------------------------------------------------------------------
// Weight transpose + bf16 split: W[K x N] row-major -> Wt hi/lo [N][K]
// ---------------------------------------------------------------------------
__global__ void wsplit_kernel(const float* __restrict__ W, int K, int N,
                              ushort* __restrict__ th, ushort* __restrict__ tl)
{
    int idx = blockIdx.x * 256 + threadIdx.x;
    if (idx >= K * N) return;
    int k = idx / N, n = idx - k * N;      // coalesced read
    float x = W[idx];
    ushort h = f2bf(x);
    th[(size_t)n * K + k] = h;
    tl[(size_t)n * K + k] = f2bf(x - bf2f(h));
}

// ---------------------------------------------------------------------------
// U split: U fp32 [M][256] -> Uh/Ul bf16 same layout
// ---------------------------------------------------------------------------
__global__ void usplit_kernel(const float* __restrict__ U,
                              ushort* __restrict__ uh, ushort* __restrict__ ul)
{
    int idx = blockIdx.x * 256 + threadIdx.x;   // cM*cD threads
    float x = U[idx];
    ushort h = f2bf(x);
    uh[idx] = h;
    ul[idx] = f2bf(x - bf2f(h));
}

// ---------------------------------------------------------------------------
// r[b][j] = tanh( concat([h,us,ue])[b] . WDw[:,j] + WDb[j] )
// ---------------------------------------------------------------------------
__global__ void r_kernel(const float* __restrict__ h, const float* __restrict__ us,
                         const float* __restrict__ ue,
                         const float* __restrict__ WDw, const float* __restrict__ WDb,
                         float* __restrict__ r)
{
    int b = blockIdx.x;
    int j = threadIdx.x;  // 128 threads
    __shared__ float x[640];
    x[j]       = h[b * cH + j];
    x[128 + j] = us[b * cD + j];
    x[256 + j] = us[b * cD + 128 + j];
    x[384 + j] = ue[b * cD + j];
    x[512 + j] = ue[b * cD + 128 + j];
    __syncthreads();
    float s = WDb[j];
    for (int k = 0; k < 640; ++k) s = fmaf(x[k], WDw[(size_t)k * cH + j], s);
    r[b * cH + j] = tanhf(s);
}

// ---------------------------------------------------------------------------
// rterm[b][n] = r[b] . W1r[:,n] + W1b[n]    (W1r = rows 256..383 of W1w)
// ---------------------------------------------------------------------------
__global__ void rterm_kernel(const float* __restrict__ r, const float* __restrict__ W1r,
                             const float* __restrict__ W1b, float* __restrict__ rterm)
{
    int b = blockIdx.y;
    int n = blockIdx.x * 256 + threadIdx.x;  // grid (8,32)
    __shared__ float rs[128];
    if (threadIdx.x < 128) rs[threadIdx.x] = r[b * cH + threadIdx.x];
    __syncthreads();
    float s = W1b[n];
    for (int k = 0; k < 128; ++k) s = fmaf(rs[k], W1r[(size_t)k * cN + n], s);
    rterm[(size_t)b * cN + n] = s;
}

// ---------------------------------------------------------------------------
// score[m] = max_p( concat([m1,m2])[m] . W3w[:,p] + W3b[p] ) -> ent region
// ---------------------------------------------------------------------------
__global__ __launch_bounds__(256)
void score_kernel(const float* __restrict__ m1, const float* __restrict__ m2,
                  const float* __restrict__ W3w, const float* __restrict__ W3b,
                  float* __restrict__ ent)
{
    __shared__ float xs[16][257];
    __shared__ float wsh[256 * 16];
    int tid = threadIdx.x;
    int m0 = blockIdx.x * 16;
    #pragma unroll
    for (int q = 0; q < 16; ++q) wsh[tid + q * 256] = W3w[tid + q * 256];
    #pragma unroll
    for (int q = 0; q < 8; ++q) {
        int f = tid + q * 256;
        int rl = f >> 7, col = f & 127;
        xs[rl][col]       = m1[(size_t)(m0 + rl) * cH + col];
        xs[rl][128 + col] = m2[(size_t)(m0 + rl) * cH + col];
    }
    __syncthreads();
    int rl = tid >> 4, p = tid & 15;
    float s = W3b[p];
    for (int k = 0; k < 256; ++k) s = fmaf(xs[rl][k], wsh[k * 16 + p], s);
    #pragma unroll
    for (int off = 8; off; off >>= 1) s = fmaxf(s, __shfl_xor(s, off));
    if (p == 0) ent[m0 + rl] = s;
}

// ---------------------------------------------------------------------------
// argmax over T per batch (first-occurrence ties), write float index,
// gather U row into us/ue
// ---------------------------------------------------------------------------
__global__ void argmax_kernel(const float* __restrict__ sc, const float* __restrict__ U,
                              float* __restrict__ uvec, float* __restrict__ outidx)
{
    int b = blockIdx.x;
    int tid = threadIdx.x;  // 256
    float bv = -3.4e38f;
    int bi = 0x7fffffff;
    for (int t = tid; t < cT; t += 256) {
        float v = sc[b * cT + t];
        if (v > bv || (v == bv && t < bi)) { bv = v; bi = t; }
    }
    __shared__ float vs[256];
    __shared__ int   is[256];
    vs[tid] = bv; is[tid] = bi;
    __syncthreads();
    for (int s = 128; s > 0; s >>= 1) {
        if (tid < s) {
            if (vs[tid + s] > vs[tid] ||
                (vs[tid + s] == vs[tid] && is[tid + s] < is[tid])) {
                vs[tid] = vs[tid + s];
                is[tid] = is[tid + s];
            }
        }
        __syncthreads();
    }
    int best = is[0];
    if (tid == 0) outidx[b] = (float)best;
    uvec[b * cD + tid % cD] = U[((size_t)b * cT + best) * cD + (tid % cD)];
}

// ---------------------------------------------------------------------------
// LSTM cell
// ---------------------------------------------------------------------------
__global__ void lstm_kernel(const float* __restrict__ us, const float* __restrict__ ue,
                            float* __restrict__ h, float* __restrict__ c,
                            const float* __restrict__ wih, const float* __restrict__ whh,
                            const float* __restrict__ bih, const float* __restrict__ bhh)
{
    int b = blockIdx.x;
    int j = threadIdx.x;  // 128
    __shared__ float x[512];
    __shared__ float hh[128];
    x[j]       = us[b * cD + j];
    x[128 + j] = us[b * cD + 128 + j];
    x[256 + j] = ue[b * cD + j];
    x[384 + j] = ue[b * cD + 128 + j];
    hh[j] = h[b * cH + j];
    __syncthreads();
    float g4[4];
    #pragma unroll
    for (int gi = 0; gi < 4; ++gi) {
        int row = gi * 128 + j;
        float s = bih[row] + bhh[row];
        const float* wr = wih + (size_t)row * 512;
        for (int k = 0; k < 512; ++k) s = fmaf(x[k], wr[k], s);
        const float* wr2 = whh + (size_t)row * 128;
        for (int k = 0; k < 128; ++k) s = fmaf(hh[k], wr2[k], s);
        g4[gi] = s;
    }
    float i_ = 1.f / (1.f + expf(-g4[0]));
    float f_ = 1.f / (1.f + expf(-g4[1]));
    float g_ = tanhf(g4[2]);
    float o_ = 1.f / (1.f + expf(-g4[3]));
    float c2 = f_ * c[b * cH + j] + i_ * g_;
    float h2 = o_ * tanhf(c2);
    c[b * cH + j] = c2;
    h[b * cH + j] = h2;
}

__global__ void init_kernel(const float* __restrict__ U, float* __restrict__ us,
                            float* __restrict__ ue, float* __restrict__ h,
                            float* __restrict__ c)
{
    int i = blockIdx.x * 256 + threadIdx.x;  // 8192 threads
    if (i < cB * cD) {
        int b = i >> 8, d = i & 255;
        us[i] = U[((size_t)b * cT + 0) * cD + d];
        ue[i] = U[((size_t)b * cT + 1) * cD + d];
    }
    if (i < cB * cH) { h[i] = 0.f; c[i] = 0.f; }
}

// ---------------------------------------------------------------------------
extern "C" void kernel_launch(void* const* d_in, const int* in_sizes, int n_in,
                              void* d_out, int out_size, void* d_ws, size_t ws_size,
                              hipStream_t stream)
{
    const float* U = (const float*)d_in[0];
    const float* WD_w[2] = {(const float*)d_in[1], (const float*)d_in[9]};
    const float* WD_b[2] = {(const float*)d_in[2], (const float*)d_in[10]};
    const float* W1_w[2] = {(const float*)d_in[3], (const float*)d_in[11]};
    const float* W1_b[2] = {(const float*)d_in[4], (const float*)d_in[12]};
    const float* W2_w[2] = {(const float*)d_in[5], (const float*)d_in[13]};
    const float* W2_b[2] = {(const float*)d_in[6], (const float*)d_in[14]};
    const float* W3_w[2] = {(const float*)d_in[7], (const float*)d_in[15]};
    const float* W3_b[2] = {(const float*)d_in[8], (const float*)d_in[16]};
    const float* wih = (const float*)d_in[17];
    const float* whh = (const float*)d_in[18];
    const float* bih = (const float*)d_in[19];
    const float* bhh = (const float*)d_in[20];

    float* ws = (float*)d_ws;
    float* m1 = ws;                               // 4M floats
    float* m2 = m1 + (size_t)cM * cH;             // 4M
    float* us = m2 + (size_t)cM * cH;
    float* ue = us + cB * cD;
    float* h  = ue + cB * cD;
    float* c  = h + cB * cH;
    float* r  = c + cB * cH;
    float* rterm = r + cB * cH;                   // 64K
    float* cur = rterm + (size_t)cB * cN;

    ushort* m1h = (ushort*)cur;                   cur += (size_t)cM * cH / 2;
    ushort* m1l = (ushort*)cur;                   cur += (size_t)cM * cH / 2;
    ushort* Uh  = (ushort*)cur;                   cur += (size_t)cM * cD / 2;
    ushort* Ul  = (ushort*)cur;                   cur += (size_t)cM * cD / 2;
    ushort* W1th[2], *W1tl[2], *W2th[2], *W2tl[2];
    for (int sd = 0; sd < 2; ++sd) {
        W1th[sd] = (ushort*)cur; cur += (size_t)cN * cD / 2;   // [2048][256]
        W1tl[sd] = (ushort*)cur; cur += (size_t)cN * cD / 2;
        W2th[sd] = (ushort*)cur; cur += (size_t)cN * cH / 2;   // [2048][128]
        W2tl[sd] = (ushort*)cur; cur += (size_t)cN * cH / 2;
    }
    float* A1[2];
    A1[0] = cur;
    A1[1] = A1[0] + (size_t)cM * cN;              // 64M floats each
    size_t need = (size_t)(A1[1] - ws) + (size_t)cM * cN;
    bool pre = ws_size >= need * sizeof(float);

    float* outf = (float*)d_out;

    init_kernel<<<32, 256, 0, stream>>>(U, us, ue, h, c);
    usplit_kernel<<<(cM * cD) / 256, 256, 0, stream>>>(U, Uh, Ul);
    for (int sd = 0; sd < 2; ++sd) {
        wsplit_kernel<<<(cD * cN) / 256, 256, 0, stream>>>(
            W1_w[sd], cD, cN, W1th[sd], W1tl[sd]);     // first 256 rows of W1
        wsplit_kernel<<<(cH * cN) / 256, 256, 0, stream>>>(
            W2_w[sd], cH, cN, W2th[sd], W2tl[sd]);
    }

    dim3 ggrid(cN / 128, cM / 128);   // 16 x 256
    if (pre) {
        // A1 = U @ W1w[0:256,:] once per weight set (constant across iters)
        for (int sd = 0; sd < 2; ++sd)
            mfma_gemm<256, false, false><<<ggrid, 256, 0, stream>>>(
                Uh, Ul, W1th[sd], W1tl[sd], nullptr, 0, A1[sd], nullptr, nullptr);
    }

    for (int it = 0; it < 4; ++it) {
        for (int sd = 0; sd < 2; ++sd) {
            r_kernel<<<32, 128, 0, stream>>>(h, us, ue, WD_w[sd], WD_b[sd], r);
            rterm_kernel<<<dim3(8, 32), 256, 0, stream>>>(
                r, W1_w[sd] + (size_t)256 * cN, W1_b[sd], rterm);
            if (pre) {
                m1_from_a1_kernel<<<16384, 256, 0, stream>>>(
                    A1[sd], rterm, m1, m1h, m1l);
            } else {
                mfma_gemm<256, true, true><<<ggrid, 256, 0, stream>>>(
                    Uh, Ul, W1th[sd], W1tl[sd], rterm, cN, m1, m1h, m1l);
            }
            // m2 = pool(m1 @ W2 + b2) -> fp32
            mfma_gemm<128, true, false><<<ggrid, 256, 0, stream>>>(
                m1h, m1l, W2th[sd], W2tl[sd], W2_b[sd], 0, m2, nullptr, nullptr);
            float* ent = outf + 64 + (size_t)(it * 2 + sd) * cB * cT;
            score_kernel<<<2048, 256, 0, stream>>>(m1, m2, W3_w[sd], W3_b[sd], ent);
            argmax_kernel<<<32, 256, 0, stream>>>(ent, U, sd ? ue : us,
                                                  outf + (sd ? 32 : 0));
        }
        lstm_kernel<<<32, 128, 0, stream>>>(us, ue, h, c, wih, whh, bih, bhh);
    }
}